// Round 1
// baseline (812.321 us; speedup 1.0000x reference)
//
#include <hip/hip_runtime.h>

// Instant-NGP hash encode (16 levels, F=2) + 32->64->64->8 MLP, outer trilinear
// over the 8 corners of a 512^3 grid. One thread per (point, outer-corner).
//
// Exactness notes (vs reference):
//  - cc = (c0+bits)/512 with integer k = c0+bits in [0,512]. pos = cc*res with
//    res = 2^(4+l) is exact fp32 => levels l>=5 have frac==0 exactly, so the
//    intra-level trilerp reduces to ONE gather (corner 0, weight 1).
//  - coarse levels l<5: p0 = k>>d, frac = (k & (2^d-1))/2^d, d = 5-l (exact).
//  - dense levels are l=0..2 ((res+1)^3 <= 2^19); l>=3 hashed.

static constexpr unsigned kT    = 1u << 19;
static constexpr unsigned kMask = kT - 1u;
static constexpr unsigned cP1   = 2654435761u;
static constexpr unsigned cP2   = 805459861u;
static constexpr int      BLOCK = 128;

__global__ __launch_bounds__(BLOCK, 2)
void ngp_fused(const float*  __restrict__ xyz,
               const float2* __restrict__ tbl,
               const float*  __restrict__ W0,
               const float*  __restrict__ W1,
               const float*  __restrict__ W2,
               const int*    __restrict__ boundp,
               float*        __restrict__ out,
               int npts)
{
    __shared__ float ldsH[64 * BLOCK];   // relu(h1) transposed: [i][tid], 32 KB

    const int tid = threadIdx.x;
    const int g   = blockIdx.x * BLOCK + tid;
    int n = g >> 3;
    const int b = g & 7;
    if (n >= npts) n = npts - 1;         // grid is sized exactly; keep flow uniform

    const float bnd = (float)boundp[0];
    const float sc  = 0.5f / bnd;        // (x+b)/(2b) ; exact vs reference for b=1

    const float pxv = xyz[n * 3 + 0];
    const float pyv = xyz[n * 3 + 1];
    const float pzv = xyz[n * 3 + 2];

    const float cxf = (pxv + bnd) * sc * 512.0f;
    const float cyf = (pyv + bnd) * sc * 512.0f;
    const float czf = (pzv + bnd) * sc * 512.0f;

    const float c0x = fminf(fmaxf(floorf(cxf), 0.0f), 511.0f);
    const float c0y = fminf(fmaxf(floorf(cyf), 0.0f), 511.0f);
    const float c0z = fminf(fmaxf(floorf(czf), 0.0f), 511.0f);
    const float frx = cxf - c0x;
    const float fry = cyf - c0y;
    const float frz = czf - c0z;

    const unsigned kx = (unsigned)c0x + (unsigned)(b & 1);
    const unsigned ky = (unsigned)c0y + (unsigned)((b >> 1) & 1);
    const unsigned kz = (unsigned)c0z + (unsigned)((b >> 2) & 1);

    const float wb = ((b & 1) ? frx : 1.0f - frx)
                   * ((b & 2) ? fry : 1.0f - fry)
                   * ((b & 4) ? frz : 1.0f - frz);

    // ---- fine levels (l = 5..15): frac == 0, single gather each ----
    const unsigned kyp = ky * cP1;       // (ky<<s)*P1 == (ky*P1)<<s  (mod 2^32)
    const unsigned kzp = kz * cP2;
    float2 gf[11];
    #pragma unroll
    for (int l = 5; l < 16; ++l) {
        const int s = l - 5;
        const unsigned idx = ((kx << s) ^ (kyp << s) ^ (kzp << s)) & kMask;
        gf[l - 5] = tbl[(size_t)l * kT + idx];
    }

    // ---- coarse levels (l = 0..4): full 8-corner trilerp ----
    float2 gc[5];
    #pragma unroll
    for (int l = 0; l < 5; ++l) {
        const int d = 5 - l;
        const unsigned m = (1u << d) - 1u;
        const float inv = 1.0f / (float)(1 << d);
        const unsigned qx = kx >> d, qy = ky >> d, qz = kz >> d;
        const float fx = (float)(kx & m) * inv;
        const float fy = (float)(ky & m) * inv;
        const float fz = (float)(kz & m) * inv;
        unsigned i0, i1, i2, i3, i4, i5, i6, i7;
        if (l < 3) {                     // dense: idx = x + y*R + z*R^2, clamp to res
            const unsigned res = 16u << l;
            const unsigned R = res + 1u, R2 = R * R;
            const unsigned x0 = (qx < res ? qx : res);
            const unsigned x1 = (qx + 1u < res ? qx + 1u : res);
            const unsigned y0 = (qy < res ? qy : res) * R;
            const unsigned y1 = (qy + 1u < res ? qy + 1u : res) * R;
            const unsigned z0 = (qz < res ? qz : res) * R2;
            const unsigned z1 = (qz + 1u < res ? qz + 1u : res) * R2;
            i0 = x0 + y0 + z0; i1 = x1 + y0 + z0; i2 = x0 + y1 + z0; i3 = x1 + y1 + z0;
            i4 = x0 + y0 + z1; i5 = x1 + y0 + z1; i6 = x0 + y1 + z1; i7 = x1 + y1 + z1;
        } else {                         // hashed: x ^ y*P1 ^ z*P2
            const unsigned hy0 = qy * cP1, hy1 = hy0 + cP1;
            const unsigned hz0 = qz * cP2, hz1 = hz0 + cP2;
            const unsigned x1u = qx + 1u;
            i0 = (qx  ^ hy0 ^ hz0) & kMask;  i1 = (x1u ^ hy0 ^ hz0) & kMask;
            i2 = (qx  ^ hy1 ^ hz0) & kMask;  i3 = (x1u ^ hy1 ^ hz0) & kMask;
            i4 = (qx  ^ hy0 ^ hz1) & kMask;  i5 = (x1u ^ hy0 ^ hz1) & kMask;
            i6 = (qx  ^ hy1 ^ hz1) & kMask;  i7 = (x1u ^ hy1 ^ hz1) & kMask;
        }
        const float2* __restrict__ base = tbl + (size_t)l * kT;
        const float2 g0 = base[i0], g1 = base[i1], g2 = base[i2], g3 = base[i3];
        const float2 g4 = base[i4], g5 = base[i5], g6 = base[i6], g7 = base[i7];
        const float wx1 = fx, wx0 = 1.0f - fx;
        const float wy1 = fy, wy0 = 1.0f - fy;
        const float wz1 = fz, wz0 = 1.0f - fz;
        const float w00 = wx0 * wy0, w10 = wx1 * wy0, w01 = wx0 * wy1, w11 = wx1 * wy1;
        const float a0 = w00 * wz0, a1 = w10 * wz0, a2 = w01 * wz0, a3 = w11 * wz0;
        const float a4 = w00 * wz1, a5 = w10 * wz1, a6 = w01 * wz1, a7 = w11 * wz1;
        float vx = a0 * g0.x + a1 * g1.x + a2 * g2.x + a3 * g3.x
                 + a4 * g4.x + a5 * g5.x + a6 * g6.x + a7 * g7.x;
        float vy = a0 * g0.y + a1 * g1.y + a2 * g2.y + a3 * g3.y
                 + a4 * g4.y + a5 * g5.y + a6 * g6.y + a7 * g7.y;
        gc[l] = make_float2(vx, vy);
    }

    // ---- layer 1: h1[j] = relu( sum_i x[i]*W0[i][j] ), per-level fused ----
    // Weight indices are compile-time/uniform => scalar s_load operands.
    float h1[64];
    #pragma unroll
    for (int j = 0; j < 64; ++j) h1[j] = 0.0f;
    #pragma unroll
    for (int l = 0; l < 16; ++l) {
        const float2 v = (l < 5) ? gc[l] : gf[l - 5];
        const float* __restrict__ w0a = W0 + (2 * l) * 64;
        const float* __restrict__ w0b = W0 + (2 * l + 1) * 64;
        #pragma unroll
        for (int j = 0; j < 64; ++j)
            h1[j] = fmaf(v.y, w0b[j], fmaf(v.x, w0a[j], h1[j]));
    }

    // relu(h1) -> LDS transposed so the layer-2 reduction loop can stay rolled
    // (dynamic i index hits LDS, not a register array => no scratch spill).
    #pragma unroll
    for (int j = 0; j < 64; ++j) ldsH[j * BLOCK + tid] = fmaxf(h1[j], 0.0f);
    __syncthreads();

    // ---- layer 2 (64->64, chunks of 16) fused with layer 3 (64->8) ----
    float facc[8];
    #pragma unroll
    for (int o = 0; o < 8; ++o) facc[o] = 0.0f;

    for (int jc = 0; jc < 4; ++jc) {          // rolled: small I-cache footprint
        float h2[16];
        #pragma unroll
        for (int j = 0; j < 16; ++j) h2[j] = 0.0f;
        const float* __restrict__ w1p = W1 + jc * 16;
        #pragma unroll 4
        for (int i = 0; i < 64; ++i) {
            const float hi = ldsH[i * BLOCK + tid];
            #pragma unroll
            for (int j = 0; j < 16; ++j)
                h2[j] = fmaf(hi, w1p[i * 64 + j], h2[j]);
        }
        const float* __restrict__ w2p = W2 + jc * 16 * 8;
        #pragma unroll
        for (int j = 0; j < 16; ++j) {
            const float v = fmaxf(h2[j], 0.0f);
            #pragma unroll
            for (int o = 0; o < 8; ++o)
                facc[o] = fmaf(v, w2p[j * 8 + o], facc[o]);
        }
    }

    // ---- combine the 8 outer corners: butterfly over 8-lane groups ----
    float vv[8];
    #pragma unroll
    for (int o = 0; o < 8; ++o) vv[o] = wb * facc[o];
    #pragma unroll
    for (int s = 1; s < 8; s <<= 1) {
        #pragma unroll
        for (int o = 0; o < 8; ++o)
            vv[o] += __shfl_xor(vv[o], s, 8);
    }
    float r = vv[0];
    #pragma unroll
    for (int o = 1; o < 8; ++o) if (b == o) r = vv[o];

    if (g < npts * 8) out[g] = r;             // coalesced: element (n, o=b)
}

extern "C" void kernel_launch(void* const* d_in, const int* in_sizes, int n_in,
                              void* d_out, int out_size, void* d_ws, size_t ws_size,
                              hipStream_t stream) {
    const float*  xyz = (const float*)d_in[0];
    const float2* tbl = (const float2*)d_in[1];
    const float*  W0  = (const float*)d_in[2];
    const float*  W1  = (const float*)d_in[3];
    const float*  W2  = (const float*)d_in[4];
    const int*    bnd = (const int*)d_in[5];
    float* out = (float*)d_out;

    const int npts  = in_sizes[0] / 3;
    const int total = npts * 8;
    const int grid  = (total + BLOCK - 1) / BLOCK;
    hipLaunchKernelGGL(ngp_fused, dim3(grid), dim3(BLOCK), 0, stream,
                       xyz, tbl, W0, W1, W2, bnd, out, npts);
}

// Round 2
// 513.133 us; speedup vs baseline: 1.5831x; 1.5831x over previous
//
#include <hip/hip_runtime.h>

// Instant-NGP hash encode (16 levels, F=2) + 32->64->64->8 MLP, outer trilinear
// over the 8 corners of a 512^3 grid. One thread per (point, outer-corner).
//
// Exactness notes (vs reference):
//  - cc = (c0+bits)/512 with integer k = c0+bits in [0,512]. pos = cc*res with
//    res = 2^(4+l) is exact fp32 => levels l>=5 have frac==0 exactly, so the
//    intra-level trilerp reduces to ONE gather (corner 0, weight 1).
//  - coarse levels l<5: p0 = k>>d, frac = (k & (2^d-1))/2^d, d = 5-l (exact).
//  - dense levels are l=0..2 ((res+1)^3 <= 2^19); l>=3 hashed.
//
// R2: relu(h1) staged in LDS as packed bf16x2 (128 B/thread, was 256 B fp32)
//     -> LDS occupancy limit 20 waves/CU (was 10). launch_bounds(128,5) caps
//     VGPR at 102 to keep 5 waves/SIMD. Hashed gathers (levels 3,4,5..15)
//     issued before dense trilerp work to deepen the memory pipeline.

static constexpr unsigned kT    = 1u << 19;
static constexpr unsigned kMask = kT - 1u;
static constexpr unsigned cP1   = 2654435761u;
static constexpr unsigned cP2   = 805459861u;
static constexpr int      BLOCK = 128;

static __device__ __forceinline__ unsigned bf16_rn(float x) {
    unsigned u = __float_as_uint(x);
    return (u + 0x7fffu + ((u >> 16) & 1u)) >> 16;   // round-to-nearest-even
}

__global__ __launch_bounds__(BLOCK, 5)
void ngp_fused(const float*  __restrict__ xyz,
               const float2* __restrict__ tbl,
               const float*  __restrict__ W0,
               const float*  __restrict__ W1,
               const float*  __restrict__ W2,
               const int*    __restrict__ boundp,
               float*        __restrict__ out,
               int npts)
{
    __shared__ unsigned ldsH[32 * BLOCK];   // relu(h1) as bf16x2, [i_pair][tid], 16 KB

    const int tid = threadIdx.x;
    const int g   = blockIdx.x * BLOCK + tid;
    const int n   = g >> 3;
    const int b   = g & 7;

    const float bnd = (float)boundp[0];
    const float sc  = 0.5f / bnd;        // (x+b)/(2b) ; exact vs reference for b=1

    const float pxv = xyz[n * 3 + 0];
    const float pyv = xyz[n * 3 + 1];
    const float pzv = xyz[n * 3 + 2];

    const float cxf = (pxv + bnd) * sc * 512.0f;
    const float cyf = (pyv + bnd) * sc * 512.0f;
    const float czf = (pzv + bnd) * sc * 512.0f;

    const float c0x = fminf(fmaxf(floorf(cxf), 0.0f), 511.0f);
    const float c0y = fminf(fmaxf(floorf(cyf), 0.0f), 511.0f);
    const float c0z = fminf(fmaxf(floorf(czf), 0.0f), 511.0f);
    const float frx = cxf - c0x;
    const float fry = cyf - c0y;
    const float frz = czf - c0z;

    const unsigned kx = (unsigned)c0x + (unsigned)(b & 1);
    const unsigned ky = (unsigned)c0y + (unsigned)((b >> 1) & 1);
    const unsigned kz = (unsigned)c0z + (unsigned)((b >> 2) & 1);

    const float wb = ((b & 1) ? frx : 1.0f - frx)
                   * ((b & 2) ? fry : 1.0f - fry)
                   * ((b & 4) ? frz : 1.0f - frz);

    // ---- fine levels (l = 5..15): frac == 0, single gather each ----
    const unsigned kyp = ky * cP1;       // (ky<<s)*P1 == (ky*P1)<<s  (mod 2^32)
    const unsigned kzp = kz * cP2;
    float2 gf[11];
    #pragma unroll
    for (int l = 5; l < 16; ++l) {
        const int s = l - 5;
        const unsigned idx = ((kx << s) ^ (kyp << s) ^ (kzp << s)) & kMask;
        gf[l - 5] = tbl[(size_t)l * kT + idx];
    }

    // ---- hashed coarse levels (l = 3,4): prefetch all 16 gathers ----
    float2 gH[2][8];
    #pragma unroll
    for (int l = 3; l < 5; ++l) {
        const int d = 5 - l;
        const unsigned qx = kx >> d, qy = ky >> d, qz = kz >> d;
        const unsigned hy0 = qy * cP1, hy1 = hy0 + cP1;
        const unsigned hz0 = qz * cP2, hz1 = hz0 + cP2;
        const unsigned x1u = qx + 1u;
        const float2* __restrict__ base = tbl + (size_t)l * kT;
        gH[l - 3][0] = base[(qx  ^ hy0 ^ hz0) & kMask];
        gH[l - 3][1] = base[(x1u ^ hy0 ^ hz0) & kMask];
        gH[l - 3][2] = base[(qx  ^ hy1 ^ hz0) & kMask];
        gH[l - 3][3] = base[(x1u ^ hy1 ^ hz0) & kMask];
        gH[l - 3][4] = base[(qx  ^ hy0 ^ hz1) & kMask];
        gH[l - 3][5] = base[(x1u ^ hy0 ^ hz1) & kMask];
        gH[l - 3][6] = base[(qx  ^ hy1 ^ hz1) & kMask];
        gH[l - 3][7] = base[(x1u ^ hy1 ^ hz1) & kMask];
    }

    // ---- coarse trilerp (dense l=0..2 gathered here; hashed from gH) ----
    float2 gc[5];
    #pragma unroll
    for (int l = 0; l < 5; ++l) {
        const int d = 5 - l;
        const unsigned m = (1u << d) - 1u;
        const float inv = 1.0f / (float)(1 << d);
        const unsigned qx = kx >> d, qy = ky >> d, qz = kz >> d;
        const float fx = (float)(kx & m) * inv;
        const float fy = (float)(ky & m) * inv;
        const float fz = (float)(kz & m) * inv;
        float2 g0, g1, g2, g3, g4, g5, g6, g7;
        if (l < 3) {                     // dense: idx = x + y*R + z*R^2, clamp to res
            const unsigned res = 16u << l;
            const unsigned R = res + 1u, R2 = R * R;
            const unsigned x0 = (qx < res ? qx : res);
            const unsigned x1 = (qx + 1u < res ? qx + 1u : res);
            const unsigned y0 = (qy < res ? qy : res) * R;
            const unsigned y1 = (qy + 1u < res ? qy + 1u : res) * R;
            const unsigned z0 = (qz < res ? qz : res) * R2;
            const unsigned z1 = (qz + 1u < res ? qz + 1u : res) * R2;
            const float2* __restrict__ base = tbl + (size_t)l * kT;
            g0 = base[x0 + y0 + z0]; g1 = base[x1 + y0 + z0];
            g2 = base[x0 + y1 + z0]; g3 = base[x1 + y1 + z0];
            g4 = base[x0 + y0 + z1]; g5 = base[x1 + y0 + z1];
            g6 = base[x0 + y1 + z1]; g7 = base[x1 + y1 + z1];
        } else {                         // hashed: prefetched above
            g0 = gH[l - 3][0]; g1 = gH[l - 3][1]; g2 = gH[l - 3][2]; g3 = gH[l - 3][3];
            g4 = gH[l - 3][4]; g5 = gH[l - 3][5]; g6 = gH[l - 3][6]; g7 = gH[l - 3][7];
        }
        const float wx1 = fx, wx0 = 1.0f - fx;
        const float wy1 = fy, wy0 = 1.0f - fy;
        const float wz1 = fz, wz0 = 1.0f - fz;
        const float w00 = wx0 * wy0, w10 = wx1 * wy0, w01 = wx0 * wy1, w11 = wx1 * wy1;
        const float a0 = w00 * wz0, a1 = w10 * wz0, a2 = w01 * wz0, a3 = w11 * wz0;
        const float a4 = w00 * wz1, a5 = w10 * wz1, a6 = w01 * wz1, a7 = w11 * wz1;
        float vx = a0 * g0.x + a1 * g1.x + a2 * g2.x + a3 * g3.x
                 + a4 * g4.x + a5 * g5.x + a6 * g6.x + a7 * g7.x;
        float vy = a0 * g0.y + a1 * g1.y + a2 * g2.y + a3 * g3.y
                 + a4 * g4.y + a5 * g5.y + a6 * g6.y + a7 * g7.y;
        gc[l] = make_float2(vx, vy);
    }

    // ---- layer 1: h1[j] = relu( sum_i x[i]*W0[i][j] ), per-level fused ----
    // Weight indices are compile-time/uniform => scalar s_load operands.
    float h1[64];
    #pragma unroll
    for (int j = 0; j < 64; ++j) h1[j] = 0.0f;
    #pragma unroll
    for (int l = 0; l < 16; ++l) {
        const float2 v = (l < 5) ? gc[l] : gf[l - 5];
        const float* __restrict__ w0a = W0 + (2 * l) * 64;
        const float* __restrict__ w0b = W0 + (2 * l + 1) * 64;
        #pragma unroll
        for (int j = 0; j < 64; ++j)
            h1[j] = fmaf(v.y, w0b[j], fmaf(v.x, w0a[j], h1[j]));
    }

    // relu(h1) -> LDS as packed bf16x2 (transposed) so the layer-2 reduction
    // can use a rolled dynamic index (LDS, not registers => no scratch spill).
    #pragma unroll
    for (int p = 0; p < 32; ++p) {
        const unsigned lo = bf16_rn(fmaxf(h1[2 * p + 0], 0.0f));
        const unsigned hi = bf16_rn(fmaxf(h1[2 * p + 1], 0.0f));
        ldsH[p * BLOCK + tid] = lo | (hi << 16);
    }
    __syncthreads();

    // ---- layer 2 (64->64, chunks of 16) fused with layer 3 (64->8) ----
    float facc[8];
    #pragma unroll
    for (int o = 0; o < 8; ++o) facc[o] = 0.0f;

    for (int jc = 0; jc < 4; ++jc) {          // rolled: small I-cache footprint
        float h2[16];
        #pragma unroll
        for (int j = 0; j < 16; ++j) h2[j] = 0.0f;
        const float* __restrict__ w1p = W1 + jc * 16;
        #pragma unroll 2
        for (int p = 0; p < 32; ++p) {
            const unsigned u = ldsH[p * BLOCK + tid];
            const float f0 = __uint_as_float(u << 16);
            const float f1 = __uint_as_float(u & 0xffff0000u);
            #pragma unroll
            for (int j = 0; j < 16; ++j)
                h2[j] = fmaf(f0, w1p[(2 * p) * 64 + j], h2[j]);
            #pragma unroll
            for (int j = 0; j < 16; ++j)
                h2[j] = fmaf(f1, w1p[(2 * p + 1) * 64 + j], h2[j]);
        }
        const float* __restrict__ w2p = W2 + jc * 16 * 8;
        #pragma unroll
        for (int j = 0; j < 16; ++j) {
            const float v = fmaxf(h2[j], 0.0f);
            #pragma unroll
            for (int o = 0; o < 8; ++o)
                facc[o] = fmaf(v, w2p[j * 8 + o], facc[o]);
        }
    }

    // ---- combine the 8 outer corners: butterfly over 8-lane groups ----
    float vv[8];
    #pragma unroll
    for (int o = 0; o < 8; ++o) vv[o] = wb * facc[o];
    #pragma unroll
    for (int s = 1; s < 8; s <<= 1) {
        #pragma unroll
        for (int o = 0; o < 8; ++o)
            vv[o] += __shfl_xor(vv[o], s, 8);
    }
    float r = vv[0];
    #pragma unroll
    for (int o = 1; o < 8; ++o) if (b == o) r = vv[o];

    out[g] = r;             // coalesced: element (n, o=b)
}

extern "C" void kernel_launch(void* const* d_in, const int* in_sizes, int n_in,
                              void* d_out, int out_size, void* d_ws, size_t ws_size,
                              hipStream_t stream) {
    const float*  xyz = (const float*)d_in[0];
    const float2* tbl = (const float2*)d_in[1];
    const float*  W0  = (const float*)d_in[2];
    const float*  W1  = (const float*)d_in[3];
    const float*  W2  = (const float*)d_in[4];
    const int*    bnd = (const int*)d_in[5];
    float* out = (float*)d_out;

    const int npts  = in_sizes[0] / 3;
    const int total = npts * 8;
    const int grid  = (total + BLOCK - 1) / BLOCK;
    hipLaunchKernelGGL(ngp_fused, dim3(grid), dim3(BLOCK), 0, stream,
                       xyz, tbl, W0, W1, W2, bnd, out, npts);
}